// Round 1
// baseline (280.637 us; speedup 1.0000x reference)
//
#include <hip/hip_runtime.h>
#include <hip/hip_bf16.h>
#include <cfloat>
#include <cmath>

#define B_ 4
#define S_ 512
#define D_ 768
#define H_ 12
#define NE_ 42
#define M_ 8
#define OFFSET_ 1
#define NE2_ (NE_*NE_)
#define OUTC_ (3*D_)   // 2304
#define HS_ (H_*S_)    // 6144

// ---------------------------------------------------------------------------
// K1: per-(b,e) entity stats: ent_emb = logsumexp over valid mentions of
// gathered sequence rows; ent_att = masked mean of gathered attention rows.
// grid = B*NE blocks, 256 threads.
// ---------------------------------------------------------------------------
__global__ void k_entity(const float* __restrict__ seq, const float* __restrict__ att,
                         const int* __restrict__ mpos, const int* __restrict__ mmask,
                         float* __restrict__ ent_emb, float* __restrict__ ent_att) {
    const int be = blockIdx.x;          // b*NE + e
    const int b  = be / NE_;

    __shared__ int sp[M_];
    __shared__ int sv[M_];
    if (threadIdx.x < M_) {
        int p  = mpos[be * M_ + threadIdx.x] + OFFSET_;
        int v  = (mmask[be * M_ + threadIdx.x] > 0) && (p < S_);
        int pc = p < 0 ? 0 : (p > S_ - 1 ? S_ - 1 : p);
        sp[threadIdx.x] = pc;
        sv[threadIdx.x] = v;
    }
    __syncthreads();

    int cnt = 0;
#pragma unroll
    for (int m = 0; m < M_; ++m) cnt += sv[m];
    const bool  has     = cnt > 0;
    const float inv_cnt = 1.0f / (float)(cnt > 0 ? cnt : 1);

    // ent_emb: logsumexp over valid mentions, per feature d
    for (int d = threadIdx.x; d < D_; d += blockDim.x) {
        float vals[M_];
        float mx = -FLT_MAX;
#pragma unroll
        for (int m = 0; m < M_; ++m) {
            float v = sv[m] ? seq[((size_t)b * S_ + sp[m]) * D_ + d] : -FLT_MAX;
            vals[m] = v;
            mx = fmaxf(mx, v);
        }
        float o = 0.0f;
        if (has) {
            float ss = 0.0f;
#pragma unroll
            for (int m = 0; m < M_; ++m)
                if (sv[m]) ss += expf(vals[m] - mx);
            o = mx + logf(ss);
        }
        ent_emb[(size_t)be * D_ + d] = o;
    }

    // ent_att: masked mean over mentions of attention[b, h, pos, :]
    for (int idx = threadIdx.x; idx < HS_; idx += blockDim.x) {
        const int h = idx >> 9;          // / S_
        const int s = idx & (S_ - 1);    // % S_
        float acc = 0.0f;
#pragma unroll
        for (int m = 0; m < M_; ++m)
            if (sv[m]) acc += att[(((size_t)b * H_ + h) * S_ + sp[m]) * S_ + s];
        ent_att[(size_t)be * HS_ + idx] = acc * inv_cnt;
    }
}

// ---------------------------------------------------------------------------
// K2: ht[b,i,j,s] = (1/H) * sum_h ent_att[b,i,h,s]*ent_att[b,j,h,s],
// then normalize over s: ht /= (sum_s ht + 1e-5).
// grid = B*NE*NE blocks, 256 threads (each thread owns s and s+256).
// ---------------------------------------------------------------------------
__global__ void k_ht(const float* __restrict__ ent_att, float* __restrict__ ht) {
    const int bij = blockIdx.x;
    const int b   = bij / NE2_;
    const int ij  = bij - b * NE2_;
    const int i   = ij / NE_;
    const int j   = ij - i * NE_;

    const float* Ai = ent_att + ((size_t)b * NE_ + i) * HS_;
    const float* Aj = ent_att + ((size_t)b * NE_ + j) * HS_;

    const int s0 = threadIdx.x;
    const int s1 = threadIdx.x + 256;
    float v0 = 0.0f, v1 = 0.0f;
#pragma unroll
    for (int h = 0; h < H_; ++h) {
        v0 += Ai[h * S_ + s0] * Aj[h * S_ + s0];
        v1 += Ai[h * S_ + s1] * Aj[h * S_ + s1];
    }
    v0 *= (1.0f / H_);
    v1 *= (1.0f / H_);

    float local = v0 + v1;
#pragma unroll
    for (int off = 32; off > 0; off >>= 1) local += __shfl_xor(local, off, 64);
    __shared__ float wsum[4];
    if ((threadIdx.x & 63) == 0) wsum[threadIdx.x >> 6] = local;
    __syncthreads();
    const float inv = 1.0f / (wsum[0] + wsum[1] + wsum[2] + wsum[3] + 1e-5f);

    ht[(size_t)bij * S_ + s0] = v0 * inv;
    ht[(size_t)bij * S_ + s1] = v1 * inv;
}

// ---------------------------------------------------------------------------
// K3: rs[b, r, d] = sum_s ht[b, r, s] * seq[b, s, d]   (r = i*NE+j)
// Tiled fp32 GEMM: BM=64, BN=64, BK=16; 256 threads, 4x4 micro-tile.
// Writes into out[..., 1536:2304].
// grid = (N/64=12, ceil(1764/64)=28, B)
// ---------------------------------------------------------------------------
#define BM_ 64
#define BN_ 64
#define BK_ 16

__global__ void k_gemm(const float* __restrict__ ht, const float* __restrict__ seq,
                       float* __restrict__ out) {
    const int b     = blockIdx.z;
    const int tileN = blockIdx.x * BN_;
    const int tileM = blockIdx.y * BM_;
    const int tid   = threadIdx.x;
    const int tx    = tid & 15;          // 0..15 -> 4 cols each
    const int ty    = tid >> 4;          // 0..15 -> 4 rows each

    const float* A = ht  + (size_t)b * NE2_ * S_;   // (1764, 512)
    const float* Bm = seq + (size_t)b * S_ * D_;    // (512, 768)

    __shared__ float As[BK_][BM_ + 1];
    __shared__ float Bs[BK_][BN_];

    float acc[4][4];
#pragma unroll
    for (int r = 0; r < 4; ++r)
#pragma unroll
        for (int c = 0; c < 4; ++c) acc[r][c] = 0.0f;

    for (int k0 = 0; k0 < S_; k0 += BK_) {
        // load A tile (rows may exceed 1764 on the last M-tile)
#pragma unroll
        for (int l = tid; l < BM_ * BK_; l += 256) {
            const int r  = l >> 4;
            const int kk = l & 15;
            const int row = tileM + r;
            As[kk][r] = (row < NE2_) ? A[(size_t)row * S_ + k0 + kk] : 0.0f;
        }
        // load B tile
#pragma unroll
        for (int l = tid; l < BK_ * BN_; l += 256) {
            const int kk = l >> 6;
            const int n  = l & 63;
            Bs[kk][n] = Bm[(size_t)(k0 + kk) * D_ + tileN + n];
        }
        __syncthreads();

#pragma unroll
        for (int k = 0; k < BK_; ++k) {
            float a[4], bb[4];
#pragma unroll
            for (int r = 0; r < 4; ++r) a[r] = As[k][ty * 4 + r];
#pragma unroll
            for (int c = 0; c < 4; ++c) bb[c] = Bs[k][tx * 4 + c];
#pragma unroll
            for (int r = 0; r < 4; ++r)
#pragma unroll
                for (int c = 0; c < 4; ++c) acc[r][c] = fmaf(a[r], bb[c], acc[r][c]);
        }
        __syncthreads();
    }

#pragma unroll
    for (int r = 0; r < 4; ++r) {
        const int row = tileM + ty * 4 + r;
        if (row < NE2_) {
            float4 v = make_float4(acc[r][0], acc[r][1], acc[r][2], acc[r][3]);
            float* dst = out + ((size_t)(b * NE2_ + row)) * OUTC_ + 2 * D_ + tileN + tx * 4;
            *reinterpret_cast<float4*>(dst) = v;
        }
    }
}

// ---------------------------------------------------------------------------
// K4: hs/ts broadcast writes: out[b,i,j,0:768] = ent_emb[b,i], [768:1536] = ent_emb[b,j]
// grid = B*NE*NE blocks, 256 threads, float4 copies.
// ---------------------------------------------------------------------------
__global__ void k_hsts(const float* __restrict__ ent_emb, float* __restrict__ out) {
    const int bij = blockIdx.x;
    const int b   = bij / NE2_;
    const int ij  = bij - b * NE2_;
    const int i   = ij / NE_;
    const int j   = ij - i * NE_;

    const float4* ei = reinterpret_cast<const float4*>(ent_emb + ((size_t)b * NE_ + i) * D_);
    const float4* ej = reinterpret_cast<const float4*>(ent_emb + ((size_t)b * NE_ + j) * D_);
    float4* o = reinterpret_cast<float4*>(out + (size_t)bij * OUTC_);

    for (int t = threadIdx.x; t < D_ / 4; t += blockDim.x) o[t] = ei[t];
    for (int t = threadIdx.x; t < D_ / 4; t += blockDim.x) o[D_ / 4 + t] = ej[t];
}

// ---------------------------------------------------------------------------
extern "C" void kernel_launch(void* const* d_in, const int* in_sizes, int n_in,
                              void* d_out, int out_size, void* d_ws, size_t ws_size,
                              hipStream_t stream) {
    const float* seq   = (const float*)d_in[0];
    const float* att   = (const float*)d_in[1];
    const int*   mpos  = (const int*)d_in[2];
    const int*   mmask = (const int*)d_in[3];
    float* out = (float*)d_out;

    float* ent_emb = (float*)d_ws;                       // B*NE*D      = 129024
    float* ent_att = ent_emb + (size_t)B_ * NE_ * D_;    // B*NE*H*S    = 1032192
    float* ht      = ent_att + (size_t)B_ * NE_ * HS_;   // B*NE*NE*S   = 3612672

    k_entity<<<B_ * NE_, 256, 0, stream>>>(seq, att, mpos, mmask, ent_emb, ent_att);
    k_ht<<<B_ * NE2_, 256, 0, stream>>>(ent_att, ht);
    k_gemm<<<dim3(D_ / BN_, (NE2_ + BM_ - 1) / BM_, B_), 256, 0, stream>>>(ht, seq, out);
    k_hsts<<<B_ * NE2_, 256, 0, stream>>>(ent_emb, out);
}

// Round 5
// 149.946 us; speedup vs baseline: 1.8716x; 1.8716x over previous
//
#include <hip/hip_runtime.h>
#include <hip/hip_bf16.h>
#include <cfloat>
#include <cmath>

#define B_ 4
#define S_ 512
#define D_ 768
#define H_ 12
#define NE_ 42
#define M_ 8
#define OFFSET_ 1
#define NE2_ (NE_*NE_)
#define OUTC_ (3*D_)   // 2304
#define HS_ (H_*S_)    // 6144
#define MPAD_ 1792     // 14 * 128, padded M for the MFMA GEMM

typedef __attribute__((ext_vector_type(8))) short short8;
typedef __attribute__((ext_vector_type(4))) float f32x4;

#define GLOAD_LDS16(g, l) __builtin_amdgcn_global_load_lds( \
    (const __attribute__((address_space(1))) unsigned int*)(g), \
    (__attribute__((address_space(3))) unsigned int*)(l), 16, 0, 0)

// ---------------------------------------------------------------------------
// K0: seqT[b][d][s] = bf16(seq[b][s][d])  — 64x64 LDS tile transpose
// grid = (D/64=12, S/64=8, B)
// ---------------------------------------------------------------------------
__global__ void k_prep(const float* __restrict__ seq, __hip_bfloat16* __restrict__ seqT) {
    const int b  = blockIdx.z;
    const int s0 = blockIdx.y * 64;
    const int d0 = blockIdx.x * 64;
    const int t  = threadIdx.x;

    __shared__ float tile[64][65];
#pragma unroll
    for (int i = 0; i < 16; ++i) {
        const int r = (t >> 6) * 16 + i;   // s within tile
        const int c = t & 63;              // d within tile
        tile[r][c] = seq[((size_t)b * S_ + s0 + r) * D_ + d0 + c];
    }
    __syncthreads();
#pragma unroll
    for (int i = 0; i < 16; ++i) {
        const int r = (t >> 6) * 16 + i;   // d within tile
        const int c = t & 63;              // s within tile
        seqT[((size_t)b * D_ + d0 + r) * S_ + s0 + c] = __float2bfloat16(tile[c][r]);
    }
}

// ---------------------------------------------------------------------------
// K1a: ent_att[b,e,h,s] = masked mean over mentions of attention[b,h,pos,s]
// grid = B*NE*H blocks, 256 threads (each thread: s and s+256)
// ---------------------------------------------------------------------------
__global__ void k_ent_att(const float* __restrict__ att, const int* __restrict__ mpos,
                          const int* __restrict__ mmask, float* __restrict__ ent_att) {
    const int beh = blockIdx.x;
    const int h   = beh % H_;
    const int be  = beh / H_;
    const int b   = be / NE_;

    __shared__ int sp[M_];
    __shared__ int sv[M_];
    if (threadIdx.x < M_) {
        int p  = mpos[be * M_ + threadIdx.x] + OFFSET_;
        int v  = (mmask[be * M_ + threadIdx.x] > 0) && (p < S_);
        int pc = p < 0 ? 0 : (p > S_ - 1 ? S_ - 1 : p);
        sp[threadIdx.x] = pc;
        sv[threadIdx.x] = v;
    }
    __syncthreads();

    int cnt = 0;
#pragma unroll
    for (int m = 0; m < M_; ++m) cnt += sv[m];
    const float inv_cnt = 1.0f / (float)(cnt > 0 ? cnt : 1);

    const float* arow = att + ((size_t)b * H_ + h) * S_ * S_;
    const int s0 = threadIdx.x;
    const int s1 = threadIdx.x + 256;
    float a0 = 0.0f, a1 = 0.0f;
#pragma unroll
    for (int m = 0; m < M_; ++m) {
        if (sv[m]) {
            a0 += arow[(size_t)sp[m] * S_ + s0];
            a1 += arow[(size_t)sp[m] * S_ + s1];
        }
    }
    float* dst = ent_att + ((size_t)be * H_ + h) * S_;
    dst[s0] = a0 * inv_cnt;
    dst[s1] = a1 * inv_cnt;
}

// ---------------------------------------------------------------------------
// K1b: ent_emb[b,e,d] = logsumexp over valid mentions of seq rows
// grid = B*NE blocks, 256 threads
// ---------------------------------------------------------------------------
__global__ void k_ent_emb(const float* __restrict__ seq, const int* __restrict__ mpos,
                          const int* __restrict__ mmask, float* __restrict__ ent_emb) {
    const int be = blockIdx.x;
    const int b  = be / NE_;

    __shared__ int sp[M_];
    __shared__ int sv[M_];
    if (threadIdx.x < M_) {
        int p  = mpos[be * M_ + threadIdx.x] + OFFSET_;
        int v  = (mmask[be * M_ + threadIdx.x] > 0) && (p < S_);
        int pc = p < 0 ? 0 : (p > S_ - 1 ? S_ - 1 : p);
        sp[threadIdx.x] = pc;
        sv[threadIdx.x] = v;
    }
    __syncthreads();

    int cnt = 0;
#pragma unroll
    for (int m = 0; m < M_; ++m) cnt += sv[m];
    const bool has = cnt > 0;

    for (int d = threadIdx.x; d < D_; d += blockDim.x) {
        float vals[M_];
        float mx = -FLT_MAX;
#pragma unroll
        for (int m = 0; m < M_; ++m) {
            float v = sv[m] ? seq[((size_t)b * S_ + sp[m]) * D_ + d] : -FLT_MAX;
            vals[m] = v;
            mx = fmaxf(mx, v);
        }
        float o = 0.0f;
        if (has) {
            float ss = 0.0f;
#pragma unroll
            for (int m = 0; m < M_; ++m)
                if (sv[m]) ss += expf(vals[m] - mx);
            o = mx + logf(ss);
        }
        ent_emb[(size_t)be * D_ + d] = o;
    }
}

// ---------------------------------------------------------------------------
// K2: ht[b,ij,s] (bf16, M padded to 1792) = normalized mean_h product
// grid = dim3(MPAD_, B_), 256 threads (each thread: s and s+256)
// ---------------------------------------------------------------------------
__global__ void k_ht(const float* __restrict__ ent_att, __hip_bfloat16* __restrict__ htb) {
    const int ij = blockIdx.x;
    const int b  = blockIdx.y;
    const int s0 = threadIdx.x;
    const int s1 = threadIdx.x + 256;
    __hip_bfloat16* dst = htb + ((size_t)b * MPAD_ + ij) * S_;

    if (ij >= NE2_) {           // zero the M padding rows
        dst[s0] = __float2bfloat16(0.0f);
        dst[s1] = __float2bfloat16(0.0f);
        return;
    }
    const int i = ij / NE_;
    const int j = ij - i * NE_;

    const float* Ai = ent_att + ((size_t)b * NE_ + i) * HS_;
    const float* Aj = ent_att + ((size_t)b * NE_ + j) * HS_;

    float v0 = 0.0f, v1 = 0.0f;
#pragma unroll
    for (int h = 0; h < H_; ++h) {
        v0 += Ai[h * S_ + s0] * Aj[h * S_ + s0];
        v1 += Ai[h * S_ + s1] * Aj[h * S_ + s1];
    }
    v0 *= (1.0f / H_);
    v1 *= (1.0f / H_);

    float local = v0 + v1;
#pragma unroll
    for (int off = 32; off > 0; off >>= 1) local += __shfl_xor(local, off, 64);
    __shared__ float wsum[4];
    if ((threadIdx.x & 63) == 0) wsum[threadIdx.x >> 6] = local;
    __syncthreads();
    const float inv = 1.0f / (wsum[0] + wsum[1] + wsum[2] + wsum[3] + 1e-5f);

    dst[s0] = __float2bfloat16(v0 * inv);
    dst[s1] = __float2bfloat16(v1 * inv);
}

// ---------------------------------------------------------------------------
// K3: rs = ht @ seq via bf16 MFMA (m97 structure).
// A = htb (MPAD x 512) bf16, B^T = seqT (768 x 512) bf16, C fp32 -> out[...,1536:].
// 128x128 tile, BK=32, 256 threads = 4 waves (2x2), each wave 64x64.
// grid = (N/128=6, MPAD/128=14, B)
// ---------------------------------------------------------------------------
__global__ void __launch_bounds__(256)
k_gemm(const __hip_bfloat16* __restrict__ htb, const __hip_bfloat16* __restrict__ seqT,
       float* __restrict__ out) {
    const int b     = blockIdx.z;
    const int tileN = blockIdx.x * 128;
    const int tileM = blockIdx.y * 128;
    const int tid   = threadIdx.x;
    const int w     = tid >> 6;
    const int lane  = tid & 63;
    const int wr    = w >> 1;          // wave row (0..1)
    const int wc    = w & 1;           // wave col (0..1)

    __shared__ unsigned short As[128 * 32];   // [row][k] 8KB
    __shared__ unsigned short Bs[128 * 32];   // [col][k] 8KB

    const __hip_bfloat16* A = htb  + (size_t)b * MPAD_ * S_;
    const __hip_bfloat16* Bt = seqT + (size_t)b * D_ * S_;

    // staging geometry: 8 chunks per tile, chunk = 16 rows x 32 cols = 1KB
    const int crow = lane >> 2;          // row within chunk (0..15)
    const int ccol = (lane & 3) * 8;     // k within chunk (0,8,16,24)

    // fragment geometry
    const int lr = lane & 15;
    const int lk = (lane >> 4) * 8;

    f32x4 acc[4][4];
#pragma unroll
    for (int mf = 0; mf < 4; ++mf)
#pragma unroll
        for (int nf = 0; nf < 4; ++nf) acc[mf][nf] = (f32x4){0.f, 0.f, 0.f, 0.f};

    for (int k0 = 0; k0 < S_; k0 += 32) {
#pragma unroll
        for (int q = 0; q < 2; ++q) {
            const int c = w * 2 + q;
            const __hip_bfloat16* ga = A + (size_t)(tileM + c * 16 + crow) * S_ + k0 + ccol;
            GLOAD_LDS16(ga, As + c * 512);
            const __hip_bfloat16* gb = Bt + (size_t)(tileN + c * 16 + crow) * S_ + k0 + ccol;
            GLOAD_LDS16(gb, Bs + c * 512);
        }
        __syncthreads();

        short8 af[4], bf[4];
#pragma unroll
        for (int mf = 0; mf < 4; ++mf)
            af[mf] = *(const short8*)&As[(wr * 64 + mf * 16 + lr) * 32 + lk];
#pragma unroll
        for (int nf = 0; nf < 4; ++nf)
            bf[nf] = *(const short8*)&Bs[(wc * 64 + nf * 16 + lr) * 32 + lk];
#pragma unroll
        for (int mf = 0; mf < 4; ++mf)
#pragma unroll
            for (int nf = 0; nf < 4; ++nf)
                acc[mf][nf] = __builtin_amdgcn_mfma_f32_16x16x32_bf16(af[mf], bf[nf], acc[mf][nf], 0, 0, 0);
        __syncthreads();
    }

    // epilogue: C/D layout col=lane&15, row=(lane>>4)*4+j
#pragma unroll
    for (int mf = 0; mf < 4; ++mf) {
        const int row0 = tileM + wr * 64 + mf * 16 + (lane >> 4) * 4;
#pragma unroll
        for (int nf = 0; nf < 4; ++nf) {
            const int col = tileN + wc * 64 + nf * 16 + (lane & 15);
#pragma unroll
            for (int j = 0; j < 4; ++j) {
                const int r = row0 + j;
                if (r < NE2_)
                    out[((size_t)(b * NE2_ + r)) * OUTC_ + 2 * D_ + col] = acc[mf][nf][j];
            }
        }
    }
}

// ---------------------------------------------------------------------------
// K4: hs/ts broadcast writes
// ---------------------------------------------------------------------------
__global__ void k_hsts(const float* __restrict__ ent_emb, float* __restrict__ out) {
    const int bij = blockIdx.x;
    const int b   = bij / NE2_;
    const int ij  = bij - b * NE2_;
    const int i   = ij / NE_;
    const int j   = ij - i * NE_;

    const float4* ei = reinterpret_cast<const float4*>(ent_emb + ((size_t)b * NE_ + i) * D_);
    const float4* ej = reinterpret_cast<const float4*>(ent_emb + ((size_t)b * NE_ + j) * D_);
    float4* o = reinterpret_cast<float4*>(out + (size_t)bij * OUTC_);

    for (int t = threadIdx.x; t < D_ / 4; t += blockDim.x) o[t] = ei[t];
    for (int t = threadIdx.x; t < D_ / 4; t += blockDim.x) o[D_ / 4 + t] = ej[t];
}

// ---------------------------------------------------------------------------
extern "C" void kernel_launch(void* const* d_in, const int* in_sizes, int n_in,
                              void* d_out, int out_size, void* d_ws, size_t ws_size,
                              hipStream_t stream) {
    const float* seq   = (const float*)d_in[0];
    const float* att   = (const float*)d_in[1];
    const int*   mpos  = (const int*)d_in[2];
    const int*   mmask = (const int*)d_in[3];
    float* out = (float*)d_out;

    // workspace layout
    float* ent_emb = (float*)d_ws;                               // B*NE*D   fp32
    float* ent_att = ent_emb + (size_t)B_ * NE_ * D_;            // B*NE*H*S fp32
    __hip_bfloat16* htb  = (__hip_bfloat16*)(ent_att + (size_t)B_ * NE_ * HS_); // B*MPAD*S bf16
    __hip_bfloat16* seqT = htb + (size_t)B_ * MPAD_ * S_;        // B*D*S bf16

    k_prep<<<dim3(D_ / 64, S_ / 64, B_), 256, 0, stream>>>(seq, seqT);
    k_ent_att<<<B_ * NE_ * H_, 256, 0, stream>>>(att, mpos, mmask, ent_att);
    k_ent_emb<<<B_ * NE_, 256, 0, stream>>>(seq, mpos, mmask, ent_emb);
    k_ht<<<dim3(MPAD_, B_), 256, 0, stream>>>(ent_att, htb);
    k_gemm<<<dim3(D_ / 128, MPAD_ / 128, B_), 256, 0, stream>>>(htb, seqT, out);
    k_hsts<<<B_ * NE2_, 256, 0, stream>>>(ent_emb, out);
}